// Round 2
// baseline (694.653 us; speedup 1.0000x reference)
//
#include <hip/hip_runtime.h>

#define NN    50000
#define EE    800000
#define EPE   850000     // EE + NN self loops
#define NPAD  50048      // multiple of 64
#define BGR   64

// packed f32 param buffer offsets (floats)
#define OW0   0
#define OWG   16384
#define OATTS 65536
#define OATTD 65920
#define OB0   66304
#define OG0   66432
#define OBE0  66560
#define OBG   66688
#define OGG   67072
#define OBGG  67456
#define OWP   67840
#define OBP   84224
#define OGP   84352
#define OBEP  84480
#define NPARAM 84608

typedef __attribute__((ext_vector_type(8))) short bf16x8;
typedef __attribute__((ext_vector_type(4))) float f32x4;

__device__ __forceinline__ float bf2f(unsigned short u) {
    return __uint_as_float(((unsigned)u) << 16);
}
__device__ __forceinline__ unsigned short f2bf(float f) {
    unsigned u = __float_as_uint(f);
    unsigned r = (u + 0x7FFFu + ((u >> 16) & 1u)) >> 16;
    return (unsigned short)r;
}
__device__ __forceinline__ float silu(float y) { return y / (1.f + __expf(-y)); }

// ---------------- dtype sniff: is the float data f32 (flag=1) or bf16 (flag=0)? ------
// x ~ N(0,1). bf16 view of bf16 data: P(|v|>=64) ~ 0. bf16 view of f32 data: the
// low-half ushorts are mantissa garbage -> ~23% have exponent field >= 134.
__global__ void sniff_kernel(const unsigned short* __restrict__ xr, int* __restrict__ flag) {
    __shared__ int cnt;
    if (threadIdx.x == 0) cnt = 0;
    __syncthreads();
    int c = 0;
    for (int i = threadIdx.x; i < 4096; i += 256) {
        unsigned e = (xr[i] >> 7) & 0xFFu;
        if (e >= 134u) c++;
    }
    atomicAdd(&cnt, c);
    __syncthreads();
    if (threadIdx.x == 0) *flag = (cnt > 64) ? 1 : 0;
}

// ---------------- canonicalize x -> bf16 workspace copy ----------------
__global__ void convert_x(const void* __restrict__ src, const int* __restrict__ flag,
                          unsigned short* __restrict__ xs, int n) {
    int f = *flag;
    int stride = gridDim.x * 256;
    for (int i = blockIdx.x * 256 + threadIdx.x; i < n; i += stride)
        xs[i] = f ? f2bf(((const float*)src)[i]) : ((const unsigned short*)src)[i];
}

// ---------------- canonicalize all weights/vectors -> packed f32 buffer ----------------
__global__ void convert_params(const void* W0, const void* Wg, const void* atts, const void* attd,
                               const void* b0, const void* g0, const void* be0,
                               const void* bg, const void* gg, const void* bgg,
                               const void* Wp, const void* bp, const void* gp, const void* bep,
                               const int* __restrict__ flag, float* __restrict__ P) {
    const void* srcs[14] = {W0, Wg, atts, attd, b0, g0, be0, bg, gg, bgg, Wp, bp, gp, bep};
    const int sizes[14] = {16384, 49152, 384, 384, 128, 128, 128, 384, 384, 384, 16384, 128, 128, 128};
    const int offs[14]  = {OW0, OWG, OATTS, OATTD, OB0, OG0, OBE0, OBG, OGG, OBGG, OWP, OBP, OGP, OBEP};
    int s = blockIdx.x;
    int f = *flag;
    const void* src = srcs[s];
    float* dst = P + offs[s];
    int n = sizes[s];
    for (int i = threadIdx.x; i < n; i += 256)
        dst[i] = f ? ((const float*)src)[i] : bf2f(((const unsigned short*)src)[i]);
}

// ---------------- weight transpose: WT[m][col][k] = W[m][k][col], bf16 ----------------
__global__ void transpose_w(const float* __restrict__ P, unsigned short* __restrict__ WT) {
    __shared__ unsigned short tile[128][129];
    int m = blockIdx.x;
    const float* src = P + (m == 0 ? OW0 : OWG + (m - 1) * 16384);
    unsigned short* dst = WT + m * 16384;
    for (int i = threadIdx.x; i < 16384; i += 256) tile[i >> 7][i & 127] = f2bf(src[i]);
    __syncthreads();
    for (int i = threadIdx.x; i < 16384; i += 256) {
        int c = i >> 7, k = i & 127;
        dst[i] = tile[k][c];
    }
}

// ---------------- CSR build ----------------
__global__ void count_edges(const int* __restrict__ eidx, int* __restrict__ counts) {
    int i = blockIdx.x * 256 + threadIdx.x;
    if (i >= EPE) return;
    int d = (i < EE) ? eidx[EE + i] : (i - EE);
    atomicAdd(&counts[d], 1);
}

__global__ void scan1(const int* __restrict__ counts, int* __restrict__ offs,
                      int* __restrict__ partials) {
    __shared__ int sm[256];
    int t = threadIdx.x, i = blockIdx.x * 256 + t;
    int x = (i < NN) ? counts[i] : 0;
    sm[t] = x; __syncthreads();
    for (int d = 1; d < 256; d <<= 1) {
        int v = (t >= d) ? sm[t - d] : 0;
        __syncthreads(); sm[t] += v; __syncthreads();
    }
    if (i < NN) offs[i] = sm[t] - x;
    if (t == 255) partials[blockIdx.x] = sm[255];
}

__global__ void scan2(int* __restrict__ partials, int nb) {
    __shared__ int sm[256];
    int t = threadIdx.x;
    int x = (t < nb) ? partials[t] : 0;
    sm[t] = x; __syncthreads();
    for (int d = 1; d < 256; d <<= 1) {
        int v = (t >= d) ? sm[t - d] : 0;
        __syncthreads(); sm[t] += v; __syncthreads();
    }
    if (t < nb) partials[t] = sm[t] - x;
}

__global__ void scan3(int* __restrict__ offs, const int* __restrict__ partials,
                      int* __restrict__ cursor) {
    int i = blockIdx.x * 256 + threadIdx.x;
    if (i < NN) {
        int v = offs[i] + partials[blockIdx.x];
        offs[i] = v; cursor[i] = v;
    }
    if (i == 0) offs[NN] = EPE;
}

__global__ void scatter_edges(const int* __restrict__ eidx, int* __restrict__ cursor,
                              int* __restrict__ csr) {
    int i = blockIdx.x * 256 + threadIdx.x;
    if (i >= EPE) return;
    int s, d;
    if (i < EE) { s = eidx[i]; d = eidx[EE + i]; } else { s = i - EE; d = i - EE; }
    int pos = atomicAdd(&cursor[d], 1);
    csr[pos] = s;
}

// ---------------- encoder GEMM: h = silu(LN(x@W0 + b0)) ----------------
__global__ __launch_bounds__(256) void gemm_encoder(
    const unsigned short* __restrict__ x, const unsigned short* __restrict__ WT,
    const float* __restrict__ b0, const float* __restrict__ g0,
    const float* __restrict__ be0, float* __restrict__ h) {
    int wave = threadIdx.x >> 6, lane = threadIdx.x & 63;
    int cl = lane & 15, q = lane >> 4;
    int row0 = blockIdx.x * 64 + wave * 16;
    int rA = row0 + cl; if (rA >= NN) rA = NN - 1;
    const unsigned short* xrow = x + rA * 128;
    int kq = q * 8;
    f32x4 acc[8];
#pragma unroll
    for (int t = 0; t < 8; ++t) acc[t] = (f32x4){0.f, 0.f, 0.f, 0.f};
#pragma unroll
    for (int k0 = 0; k0 < 128; k0 += 32) {
        bf16x8 a = *(const bf16x8*)(xrow + k0 + kq);
#pragma unroll
        for (int t = 0; t < 8; ++t) {
            bf16x8 b = *(const bf16x8*)(WT + (t * 16 + cl) * 128 + k0 + kq);
            acc[t] = __builtin_amdgcn_mfma_f32_16x16x32_bf16(a, b, acc[t], 0, 0, 0);
        }
    }
    float bcol[8], gcol[8], becol[8];
#pragma unroll
    for (int t = 0; t < 8; ++t) {
        int c = t * 16 + cl;
        bcol[t] = b0[c]; gcol[t] = g0[c]; becol[t] = be0[c];
    }
#pragma unroll
    for (int r = 0; r < 4; ++r) {
        int row = row0 + q * 4 + r;
        float v[8], s = 0.f, ss = 0.f;
#pragma unroll
        for (int t = 0; t < 8; ++t) {
            v[t] = acc[t][r] + bcol[t];
            s += v[t]; ss += v[t] * v[t];
        }
#pragma unroll
        for (int m = 1; m <= 8; m <<= 1) {
            s += __shfl_xor(s, m, 64); ss += __shfl_xor(ss, m, 64);
        }
        float mu = s * (1.f / 128.f);
        float var = ss * (1.f / 128.f) - mu * mu;
        float rstd = rsqrtf(var + 1e-5f);
        if (row < NN) {
#pragma unroll
            for (int t = 0; t < 8; ++t) {
                float y = (v[t] - mu) * rstd * gcol[t] + becol[t];
                h[row * 128 + t * 16 + cl] = silu(y);
            }
        }
    }
}

// ---------------- GAT GEMM: hh = h@Wg[l] (bf16), a_s/a_d dot products ----------------
__global__ __launch_bounds__(256) void gemm_gat(
    const float* __restrict__ h, const unsigned short* __restrict__ WT,
    const float* __restrict__ atts, const float* __restrict__ attd,
    unsigned short* __restrict__ hh, float* __restrict__ a_s, float* __restrict__ a_d) {
    int wave = threadIdx.x >> 6, lane = threadIdx.x & 63;
    int cl = lane & 15, q = lane >> 4;
    int row0 = blockIdx.x * 64 + wave * 16;
    int rA = row0 + cl; if (rA >= NN) rA = NN - 1;
    const float* hrow = h + rA * 128;
    int kq = q * 8;
    f32x4 acc[8];
#pragma unroll
    for (int t = 0; t < 8; ++t) acc[t] = (f32x4){0.f, 0.f, 0.f, 0.f};
#pragma unroll
    for (int k0 = 0; k0 < 128; k0 += 32) {
        f32x4 f0 = *(const f32x4*)(hrow + k0 + kq);
        f32x4 f1 = *(const f32x4*)(hrow + k0 + kq + 4);
        bf16x8 a;
#pragma unroll
        for (int j = 0; j < 4; ++j) {
            a[j] = (short)f2bf(f0[j]);
            a[4 + j] = (short)f2bf(f1[j]);
        }
#pragma unroll
        for (int t = 0; t < 8; ++t) {
            bf16x8 b = *(const bf16x8*)(WT + (t * 16 + cl) * 128 + k0 + kq);
            acc[t] = __builtin_amdgcn_mfma_f32_16x16x32_bf16(a, b, acc[t], 0, 0, 0);
        }
    }
#pragma unroll
    for (int r = 0; r < 4; ++r) {
        int row = row0 + q * 4 + r;
        if (row < NN) {
#pragma unroll
            for (int t = 0; t < 8; ++t)
                hh[row * 128 + t * 16 + cl] = f2bf(acc[t][r]);
        }
    }
    float as_lo[4], as_hi[4], ad_lo[4], ad_hi[4];
#pragma unroll
    for (int hd = 0; hd < 4; ++hd) {
        as_lo[hd] = atts[hd * 32 + cl];      as_hi[hd] = atts[hd * 32 + 16 + cl];
        ad_lo[hd] = attd[hd * 32 + cl];      ad_hi[hd] = attd[hd * 32 + 16 + cl];
    }
#pragma unroll
    for (int r = 0; r < 4; ++r) {
        int row = row0 + q * 4 + r;
        float ps[4], pd[4];
#pragma unroll
        for (int hd = 0; hd < 4; ++hd) {
            float v0 = acc[2 * hd][r], v1 = acc[2 * hd + 1][r];
            ps[hd] = v0 * as_lo[hd] + v1 * as_hi[hd];
            pd[hd] = v0 * ad_lo[hd] + v1 * ad_hi[hd];
        }
#pragma unroll
        for (int m = 1; m <= 8; m <<= 1) {
#pragma unroll
            for (int hd = 0; hd < 4; ++hd) {
                ps[hd] += __shfl_xor(ps[hd], m, 64);
                pd[hd] += __shfl_xor(pd[hd], m, 64);
            }
        }
        if (row < NN && cl < 4) {
            float vs = (cl == 0) ? ps[0] : (cl == 1) ? ps[1] : (cl == 2) ? ps[2] : ps[3];
            float vd = (cl == 0) ? pd[0] : (cl == 1) ? pd[1] : (cl == 2) ? pd[2] : pd[3];
            a_s[row * 4 + cl] = vs;
            a_d[row * 4 + cl] = vd;
        }
    }
}

// ---------------- per-dst-node aggregation + LN + SiLU + residual (in place on h) ------
__global__ __launch_bounds__(256) void gat_aggregate(
    const int* __restrict__ offs, const int* __restrict__ csr,
    const float* __restrict__ a_s, const float* __restrict__ a_d,
    const unsigned short* __restrict__ hh, float* __restrict__ h,
    const float* __restrict__ bg, const float* __restrict__ gg,
    const float* __restrict__ bgg) {
    int node = blockIdx.x * 4 + (threadIdx.x >> 6);
    int lane = threadIdx.x & 63;
    if (node >= NN) return;
    int e0 = offs[node], e1 = offs[node + 1];
    f32x4 adv = *(const f32x4*)(a_d + node * 4);
    float m0 = -1e30f, m1 = -1e30f, m2 = -1e30f, m3 = -1e30f;
    for (int e = e0 + lane; e < e1; e += 64) {
        int s = csr[e];
        f32x4 as = *(const f32x4*)(a_s + s * 4);
        float t0 = as[0] + adv[0]; t0 = (t0 > 0.f) ? t0 : 0.2f * t0; m0 = fmaxf(m0, t0);
        float t1 = as[1] + adv[1]; t1 = (t1 > 0.f) ? t1 : 0.2f * t1; m1 = fmaxf(m1, t1);
        float t2 = as[2] + adv[2]; t2 = (t2 > 0.f) ? t2 : 0.2f * t2; m2 = fmaxf(m2, t2);
        float t3 = as[3] + adv[3]; t3 = (t3 > 0.f) ? t3 : 0.2f * t3; m3 = fmaxf(m3, t3);
    }
#pragma unroll
    for (int m = 1; m <= 32; m <<= 1) {
        m0 = fmaxf(m0, __shfl_xor(m0, m, 64));
        m1 = fmaxf(m1, __shfl_xor(m1, m, 64));
        m2 = fmaxf(m2, __shfl_xor(m2, m, 64));
        m3 = fmaxf(m3, __shfl_xor(m3, m, 64));
    }
    float d0 = 0.f, d1 = 0.f, d2 = 0.f, d3 = 0.f;
    for (int e = e0 + lane; e < e1; e += 64) {
        int s = csr[e];
        f32x4 as = *(const f32x4*)(a_s + s * 4);
        float t0 = as[0] + adv[0]; t0 = (t0 > 0.f) ? t0 : 0.2f * t0; d0 += __expf(t0 - m0);
        float t1 = as[1] + adv[1]; t1 = (t1 > 0.f) ? t1 : 0.2f * t1; d1 += __expf(t1 - m1);
        float t2 = as[2] + adv[2]; t2 = (t2 > 0.f) ? t2 : 0.2f * t2; d2 += __expf(t2 - m2);
        float t3 = as[3] + adv[3]; t3 = (t3 > 0.f) ? t3 : 0.2f * t3; d3 += __expf(t3 - m3);
    }
#pragma unroll
    for (int m = 1; m <= 32; m <<= 1) {
        d0 += __shfl_xor(d0, m, 64);
        d1 += __shfl_xor(d1, m, 64);
        d2 += __shfl_xor(d2, m, 64);
        d3 += __shfl_xor(d3, m, 64);
    }
    int c0 = lane * 2;
    int hd = lane >> 4;
    float adh = (hd == 0) ? adv[0] : (hd == 1) ? adv[1] : (hd == 2) ? adv[2] : adv[3];
    float mh  = (hd == 0) ? m0 : (hd == 1) ? m1 : (hd == 2) ? m2 : m3;
    float dh  = (hd == 0) ? d0 : (hd == 1) ? d1 : (hd == 2) ? d2 : d3;
    float ih = 1.f / dh;
    float acc0 = 0.f, acc1 = 0.f;
    for (int e = e0; e < e1; ++e) {
        int s = csr[e];
        float asv = a_s[s * 4 + hd];
        float eh = asv + adh; eh = (eh > 0.f) ? eh : 0.2f * eh;
        float alpha = __expf(eh - mh) * ih;
        unsigned hv = *(const unsigned*)(hh + s * 128 + c0);
        acc0 += alpha * bf2f((unsigned short)(hv & 0xFFFFu));
        acc1 += alpha * bf2f((unsigned short)(hv >> 16));
    }
    float o0 = acc0 + bg[c0];
    float o1 = acc1 + bg[c0 + 1];
    float s = o0 + o1, ss = o0 * o0 + o1 * o1;
#pragma unroll
    for (int m = 1; m <= 32; m <<= 1) {
        s += __shfl_xor(s, m, 64); ss += __shfl_xor(ss, m, 64);
    }
    float mu = s * (1.f / 128.f);
    float var = ss * (1.f / 128.f) - mu * mu;
    float rstd = rsqrtf(var + 1e-5f);
    float y0 = (o0 - mu) * rstd * gg[c0] + bgg[c0];
    float y1 = (o1 - mu) * rstd * gg[c0 + 1] + bgg[c0 + 1];
    float id0 = h[node * 128 + c0], id1 = h[node * 128 + c0 + 1];
    h[node * 128 + c0]     = silu(y0) + id0;
    h[node * 128 + c0 + 1] = silu(y1) + id1;
}

// ---------------- mean pool per graph (batch is sorted) ----------------
__global__ void pool_kernel(const float* __restrict__ h, const int* __restrict__ batch,
                            float* __restrict__ pooled, float* __restrict__ cntArr) {
    int c = threadIdx.x;
    int r0 = blockIdx.x * 64;
    int rend = r0 + 64; if (rend > NN) rend = NN;
    int cur = batch[r0];
    float acc = 0.f;
    int run = 0;
    for (int r = r0; r < rend; ++r) {
        int b = batch[r];
        float v = h[r * 128 + c];
        if (b != cur) {
            atomicAdd(&pooled[cur * 128 + c], acc);
            if (c == 0) atomicAdd(&cntArr[cur], (float)run);
            acc = 0.f; run = 0; cur = b;
        }
        acc += v; run++;
    }
    atomicAdd(&pooled[cur * 128 + c], acc);
    if (c == 0) atomicAdd(&cntArr[cur], (float)run);
}

// ---------------- head: silu(LN(pooled/cnt @ Wp + bp)) -> out (dtype per flag) --------
__global__ void final_kernel(const float* __restrict__ pooled, const float* __restrict__ cntArr,
                             const float* __restrict__ Wp, const float* __restrict__ bp,
                             const float* __restrict__ gp, const float* __restrict__ bep,
                             const int* __restrict__ flag, void* __restrict__ outv) {
    __shared__ float p[128];
    __shared__ float red[128];
    int g = blockIdx.x, c = threadIdx.x;
    float cnt = cntArr[g]; if (cnt < 1.f) cnt = 1.f;
    p[c] = pooled[g * 128 + c] / cnt;
    __syncthreads();
    float acc = bp[c];
    for (int k = 0; k < 128; ++k) acc += p[k] * Wp[k * 128 + c];
    red[c] = acc;
    __syncthreads();
    if (c < 64) {
        float s = red[c] + red[c + 64];
#pragma unroll
        for (int m = 1; m <= 32; m <<= 1) s += __shfl_xor(s, m, 64);
        if (c == 0) red[0] = s;
    }
    __syncthreads();
    float mu = red[0] * (1.f / 128.f);
    __syncthreads();
    float dv = acc - mu;
    red[c] = dv * dv;
    __syncthreads();
    if (c < 64) {
        float s = red[c] + red[c + 64];
#pragma unroll
        for (int m = 1; m <= 32; m <<= 1) s += __shfl_xor(s, m, 64);
        if (c == 0) red[0] = s;
    }
    __syncthreads();
    float var = red[0] * (1.f / 128.f);
    float rstd = rsqrtf(var + 1e-5f);
    float y = dv * rstd * gp[c] + bep[c];
    float r = silu(y);
    if (*flag) ((float*)outv)[g * 128 + c] = r;
    else       ((unsigned short*)outv)[g * 128 + c] = f2bf(r);
}

extern "C" void kernel_launch(void* const* d_in, const int* in_sizes, int n_in,
                              void* d_out, int out_size, void* d_ws, size_t ws_size,
                              hipStream_t stream) {
    const void* x    = d_in[0];
    const int*  eidx = (const int*)d_in[1];
    const int*  batch= (const int*)d_in[2];

    char* ws = (char*)d_ws;
    size_t off = 0;
    auto alloc = [&](size_t bytes) {
        void* p = ws + off;
        off = (off + bytes + 255) & ~(size_t)255;
        return p;
    };
    int*            flag   = (int*)alloc(256);
    unsigned short* xs     = (unsigned short*)alloc((size_t)NN * 128 * 2);
    float*          P      = (float*)alloc((size_t)NPARAM * 4);
    float*          h      = (float*)alloc((size_t)NPAD * 128 * 4);
    unsigned short* hh     = (unsigned short*)alloc((size_t)NN * 128 * 2);
    float*          a_s    = (float*)alloc((size_t)NN * 4 * 4);
    float*          a_d    = (float*)alloc((size_t)NN * 4 * 4);
    int*            offs   = (int*)alloc((size_t)(NN + 1) * 4);
    int*            cursor = (int*)alloc((size_t)NN * 4);
    int*            counts = (int*)alloc((size_t)NN * 4);
    int*            csr    = (int*)alloc((size_t)EPE * 4);
    int*            parts  = (int*)alloc(256 * 4);
    unsigned short* WT     = (unsigned short*)alloc(4 * 16384 * 2);
    float*          pooled = (float*)alloc((size_t)(BGR * 128 + BGR) * 4);
    float*          cntArr = pooled + BGR * 128;

    hipMemsetAsync(counts, 0, (size_t)NN * 4, stream);
    hipMemsetAsync(pooled, 0, (size_t)(BGR * 128 + BGR) * 4, stream);

    sniff_kernel<<<1, 256, 0, stream>>>((const unsigned short*)x, flag);
    convert_x<<<4096, 256, 0, stream>>>(x, flag, xs, NN * 128);
    convert_params<<<14, 256, 0, stream>>>(d_in[3], d_in[7], d_in[8], d_in[9],
                                           d_in[4], d_in[5], d_in[6],
                                           d_in[10], d_in[11], d_in[12],
                                           d_in[13], d_in[14], d_in[15], d_in[16],
                                           flag, P);
    transpose_w<<<4, 256, 0, stream>>>(P, WT);

    count_edges<<<(EPE + 255) / 256, 256, 0, stream>>>(eidx, counts);
    int nb = (NN + 255) / 256;
    scan1<<<nb, 256, 0, stream>>>(counts, offs, parts);
    scan2<<<1, 256, 0, stream>>>(parts, nb);
    scan3<<<nb, 256, 0, stream>>>(offs, parts, cursor);
    scatter_edges<<<(EPE + 255) / 256, 256, 0, stream>>>(eidx, cursor, csr);

    gemm_encoder<<<NPAD / 64, 256, 0, stream>>>(xs, WT, P + OB0, P + OG0, P + OBE0, h);
    for (int l = 0; l < 3; ++l) {
        gemm_gat<<<NPAD / 64, 256, 0, stream>>>(h, WT + (l + 1) * 16384,
                                                P + OATTS + l * 128, P + OATTD + l * 128,
                                                hh, a_s, a_d);
        gat_aggregate<<<NN / 4, 256, 0, stream>>>(offs, csr, a_s, a_d, hh, h,
                                                  P + OBG + l * 128, P + OGG + l * 128,
                                                  P + OBGG + l * 128);
    }
    pool_kernel<<<(NN + 63) / 64, 128, 0, stream>>>(h, batch, pooled, cntArr);
    final_kernel<<<BGR, 128, 0, stream>>>(pooled, cntArr, P + OWP, P + OBP, P + OGP, P + OBEP,
                                          flag, d_out);
}

// Round 3
// 582.985 us; speedup vs baseline: 1.1915x; 1.1915x over previous
//
#include <hip/hip_runtime.h>

#define NN    50000
#define EE    800000
#define EPE   850000     // EE + NN self loops
#define NPAD  50048      // multiple of 64
#define BGR   64

// packed f32 param buffer offsets (floats)
#define OW0   0
#define OWG   16384
#define OATTS 65536
#define OATTD 65920
#define OB0   66304
#define OG0   66432
#define OBE0  66560
#define OBG   66688
#define OGG   67072
#define OBGG  67456
#define OWP   67840
#define OBP   84224
#define OGP   84352
#define OBEP  84480
#define NPARAM 84608

typedef __attribute__((ext_vector_type(8))) short bf16x8;
typedef __attribute__((ext_vector_type(4))) float f32x4;

__device__ __forceinline__ float bf2f(unsigned short u) {
    return __uint_as_float(((unsigned)u) << 16);
}
__device__ __forceinline__ unsigned short f2bf(float f) {
    unsigned u = __float_as_uint(f);
    unsigned r = (u + 0x7FFFu + ((u >> 16) & 1u)) >> 16;
    return (unsigned short)r;
}
__device__ __forceinline__ float silu(float y) { return y / (1.f + __expf(-y)); }

// ---------------- dtype sniff: f32 (flag=1) vs bf16 (flag=0) ----------------
__global__ void sniff_kernel(const unsigned short* __restrict__ xr, int* __restrict__ flag) {
    __shared__ int cnt;
    if (threadIdx.x == 0) cnt = 0;
    __syncthreads();
    int c = 0;
    for (int i = threadIdx.x; i < 4096; i += 256) {
        unsigned e = (xr[i] >> 7) & 0xFFu;
        if (e >= 134u) c++;
    }
    atomicAdd(&cnt, c);
    __syncthreads();
    if (threadIdx.x == 0) *flag = (cnt > 64) ? 1 : 0;
}

// ---------------- canonicalize x -> bf16 workspace copy ----------------
__global__ void convert_x(const void* __restrict__ src, const int* __restrict__ flag,
                          unsigned short* __restrict__ xs, int n) {
    int f = *flag;
    int stride = gridDim.x * 256;
    for (int i = blockIdx.x * 256 + threadIdx.x; i < n; i += stride)
        xs[i] = f ? f2bf(((const float*)src)[i]) : ((const unsigned short*)src)[i];
}

// ---------------- canonicalize all weights/vectors -> packed f32 buffer ----------------
__global__ void convert_params(const void* W0, const void* Wg, const void* atts, const void* attd,
                               const void* b0, const void* g0, const void* be0,
                               const void* bg, const void* gg, const void* bgg,
                               const void* Wp, const void* bp, const void* gp, const void* bep,
                               const int* __restrict__ flag, float* __restrict__ P) {
    const void* srcs[14] = {W0, Wg, atts, attd, b0, g0, be0, bg, gg, bgg, Wp, bp, gp, bep};
    const int sizes[14] = {16384, 49152, 384, 384, 128, 128, 128, 384, 384, 384, 16384, 128, 128, 128};
    const int offs[14]  = {OW0, OWG, OATTS, OATTD, OB0, OG0, OBE0, OBG, OGG, OBGG, OWP, OBP, OGP, OBEP};
    int s = blockIdx.x;
    int f = *flag;
    const void* src = srcs[s];
    float* dst = P + offs[s];
    int n = sizes[s];
    for (int i = threadIdx.x; i < n; i += 256)
        dst[i] = f ? ((const float*)src)[i] : bf2f(((const unsigned short*)src)[i]);
}

// ---------------- weight transpose: WT[m][col][k] = W[m][k][col], bf16 ----------------
__global__ void transpose_w(const float* __restrict__ P, unsigned short* __restrict__ WT) {
    __shared__ unsigned short tile[128][129];
    int m = blockIdx.x;
    const float* src = P + (m == 0 ? OW0 : OWG + (m - 1) * 16384);
    unsigned short* dst = WT + m * 16384;
    for (int i = threadIdx.x; i < 16384; i += 256) tile[i >> 7][i & 127] = f2bf(src[i]);
    __syncthreads();
    for (int i = threadIdx.x; i < 16384; i += 256) {
        int c = i >> 7, k = i & 127;
        dst[i] = tile[k][c];
    }
}

// ---------------- CSR build ----------------
__global__ void count_edges(const int* __restrict__ eidx, int* __restrict__ counts) {
    int i = blockIdx.x * 256 + threadIdx.x;
    if (i >= EPE) return;
    int d = (i < EE) ? eidx[EE + i] : (i - EE);
    atomicAdd(&counts[d], 1);
}

__global__ void scan1(const int* __restrict__ counts, int* __restrict__ offs,
                      int* __restrict__ partials) {
    __shared__ int sm[256];
    int t = threadIdx.x, i = blockIdx.x * 256 + t;
    int x = (i < NN) ? counts[i] : 0;
    sm[t] = x; __syncthreads();
    for (int d = 1; d < 256; d <<= 1) {
        int v = (t >= d) ? sm[t - d] : 0;
        __syncthreads(); sm[t] += v; __syncthreads();
    }
    if (i < NN) offs[i] = sm[t] - x;
    if (t == 255) partials[blockIdx.x] = sm[255];
}

__global__ void scan2(int* __restrict__ partials, int nb) {
    __shared__ int sm[256];
    int t = threadIdx.x;
    int x = (t < nb) ? partials[t] : 0;
    sm[t] = x; __syncthreads();
    for (int d = 1; d < 256; d <<= 1) {
        int v = (t >= d) ? sm[t - d] : 0;
        __syncthreads(); sm[t] += v; __syncthreads();
    }
    if (t < nb) partials[t] = sm[t] - x;
}

__global__ void scan3(int* __restrict__ offs, const int* __restrict__ partials,
                      int* __restrict__ cursor) {
    int i = blockIdx.x * 256 + threadIdx.x;
    if (i < NN) {
        int v = offs[i] + partials[blockIdx.x];
        offs[i] = v; cursor[i] = v;
    }
    if (i == 0) offs[NN] = EPE;
}

__global__ void scatter_edges(const int* __restrict__ eidx, int* __restrict__ cursor,
                              int* __restrict__ csr) {
    int i = blockIdx.x * 256 + threadIdx.x;
    if (i >= EPE) return;
    int s, d;
    if (i < EE) { s = eidx[i]; d = eidx[EE + i]; } else { s = i - EE; d = i - EE; }
    int pos = atomicAdd(&cursor[d], 1);
    csr[pos] = s;
}

// ---------------- encoder GEMM: h = silu(LN(x@W0 + b0)) ----------------
__global__ __launch_bounds__(256) void gemm_encoder(
    const unsigned short* __restrict__ x, const unsigned short* __restrict__ WT,
    const float* __restrict__ b0, const float* __restrict__ g0,
    const float* __restrict__ be0, float* __restrict__ h,
    unsigned short* __restrict__ hb) {
    int wave = threadIdx.x >> 6, lane = threadIdx.x & 63;
    int cl = lane & 15, q = lane >> 4;
    int row0 = blockIdx.x * 64 + wave * 16;
    int rA = row0 + cl; if (rA >= NN) rA = NN - 1;
    const unsigned short* xrow = x + rA * 128;
    int kq = q * 8;
    f32x4 acc[8];
#pragma unroll
    for (int t = 0; t < 8; ++t) acc[t] = (f32x4){0.f, 0.f, 0.f, 0.f};
#pragma unroll
    for (int k0 = 0; k0 < 128; k0 += 32) {
        bf16x8 a = *(const bf16x8*)(xrow + k0 + kq);
#pragma unroll
        for (int t = 0; t < 8; ++t) {
            bf16x8 b = *(const bf16x8*)(WT + (t * 16 + cl) * 128 + k0 + kq);
            acc[t] = __builtin_amdgcn_mfma_f32_16x16x32_bf16(a, b, acc[t], 0, 0, 0);
        }
    }
    float bcol[8], gcol[8], becol[8];
#pragma unroll
    for (int t = 0; t < 8; ++t) {
        int c = t * 16 + cl;
        bcol[t] = b0[c]; gcol[t] = g0[c]; becol[t] = be0[c];
    }
#pragma unroll
    for (int r = 0; r < 4; ++r) {
        int row = row0 + q * 4 + r;
        float v[8], s = 0.f, ss = 0.f;
#pragma unroll
        for (int t = 0; t < 8; ++t) {
            v[t] = acc[t][r] + bcol[t];
            s += v[t]; ss += v[t] * v[t];
        }
#pragma unroll
        for (int m = 1; m <= 8; m <<= 1) {
            s += __shfl_xor(s, m, 64); ss += __shfl_xor(ss, m, 64);
        }
        float mu = s * (1.f / 128.f);
        float var = ss * (1.f / 128.f) - mu * mu;
        float rstd = rsqrtf(var + 1e-5f);
        if (row < NN) {
#pragma unroll
            for (int t = 0; t < 8; ++t) {
                float y = (v[t] - mu) * rstd * gcol[t] + becol[t];
                float r2 = silu(y);
                h[row * 128 + t * 16 + cl] = r2;
                if (hb) hb[row * 128 + t * 16 + cl] = f2bf(r2);
            }
        }
    }
}

// ---------------- GAT GEMM: hh = h@Wg[l] (bf16), a_s/a_d dot products ----------------
template<int HB>
__global__ __launch_bounds__(256) void gemm_gat(
    const float* __restrict__ h, const unsigned short* __restrict__ hbin,
    const unsigned short* __restrict__ WT,
    const float* __restrict__ atts, const float* __restrict__ attd,
    unsigned short* __restrict__ hh, float* __restrict__ a_s, float* __restrict__ a_d) {
    int wave = threadIdx.x >> 6, lane = threadIdx.x & 63;
    int cl = lane & 15, q = lane >> 4;
    int row0 = blockIdx.x * 64 + wave * 16;
    int rA = row0 + cl; if (rA >= NN) rA = NN - 1;
    int kq = q * 8;
    f32x4 acc[8];
#pragma unroll
    for (int t = 0; t < 8; ++t) acc[t] = (f32x4){0.f, 0.f, 0.f, 0.f};
#pragma unroll
    for (int k0 = 0; k0 < 128; k0 += 32) {
        bf16x8 a;
        if constexpr (HB) {
            a = *(const bf16x8*)(hbin + rA * 128 + k0 + kq);
        } else {
            const float* hrow = h + rA * 128;
            f32x4 f0 = *(const f32x4*)(hrow + k0 + kq);
            f32x4 f1 = *(const f32x4*)(hrow + k0 + kq + 4);
#pragma unroll
            for (int j = 0; j < 4; ++j) {
                a[j] = (short)f2bf(f0[j]);
                a[4 + j] = (short)f2bf(f1[j]);
            }
        }
#pragma unroll
        for (int t = 0; t < 8; ++t) {
            bf16x8 b = *(const bf16x8*)(WT + (t * 16 + cl) * 128 + k0 + kq);
            acc[t] = __builtin_amdgcn_mfma_f32_16x16x32_bf16(a, b, acc[t], 0, 0, 0);
        }
    }
#pragma unroll
    for (int r = 0; r < 4; ++r) {
        int row = row0 + q * 4 + r;
        if (row < NN) {
#pragma unroll
            for (int t = 0; t < 8; ++t)
                hh[row * 128 + t * 16 + cl] = f2bf(acc[t][r]);
        }
    }
    float as_lo[4], as_hi[4], ad_lo[4], ad_hi[4];
#pragma unroll
    for (int hd = 0; hd < 4; ++hd) {
        as_lo[hd] = atts[hd * 32 + cl];      as_hi[hd] = atts[hd * 32 + 16 + cl];
        ad_lo[hd] = attd[hd * 32 + cl];      ad_hi[hd] = attd[hd * 32 + 16 + cl];
    }
#pragma unroll
    for (int r = 0; r < 4; ++r) {
        int row = row0 + q * 4 + r;
        float ps[4], pd[4];
#pragma unroll
        for (int hd = 0; hd < 4; ++hd) {
            float v0 = acc[2 * hd][r], v1 = acc[2 * hd + 1][r];
            ps[hd] = v0 * as_lo[hd] + v1 * as_hi[hd];
            pd[hd] = v0 * ad_lo[hd] + v1 * ad_hi[hd];
        }
#pragma unroll
        for (int m = 1; m <= 8; m <<= 1) {
#pragma unroll
            for (int hd = 0; hd < 4; ++hd) {
                ps[hd] += __shfl_xor(ps[hd], m, 64);
                pd[hd] += __shfl_xor(pd[hd], m, 64);
            }
        }
        if (row < NN && cl < 4) {
            float vs = (cl == 0) ? ps[0] : (cl == 1) ? ps[1] : (cl == 2) ? ps[2] : ps[3];
            float vd = (cl == 0) ? pd[0] : (cl == 1) ? pd[1] : (cl == 2) ? pd[2] : pd[3];
            a_s[row * 4 + cl] = vs;
            a_d[row * 4 + cl] = vd;
        }
    }
}

// ---------------- single-pass aggregation + LN + SiLU + residual (in place on h) ------
// softmax stabilized by the self-loop logit (shift-invariance); denom fused into the
// same serial edge loop; no cross-lane reductions except the LN sums.
__global__ __launch_bounds__(256) void gat_aggregate(
    const int* __restrict__ offs, const int* __restrict__ csr,
    const float* __restrict__ a_s, const float* __restrict__ a_d,
    const unsigned short* __restrict__ hh, float* __restrict__ h,
    unsigned short* __restrict__ hb,
    const float* __restrict__ bg, const float* __restrict__ gg,
    const float* __restrict__ bgg) {
    int node = blockIdx.x * 4 + (threadIdx.x >> 6);
    int lane = threadIdx.x & 63;
    if (node >= NN) return;
    int e0 = offs[node], e1 = offs[node + 1];
    int c0 = lane * 2;
    int hd = lane >> 4;
    float adh = a_d[node * 4 + hd];
    float es = a_s[node * 4 + hd] + adh;
    es = (es > 0.f) ? es : 0.2f * es;               // self-loop logit = stabilizer
    float da = 0.f, a0 = 0.f, a1 = 0.f;
    float db = 0.f, b0v = 0.f, b1v = 0.f;
    int e = e0;
    for (; e + 2 <= e1; e += 2) {
        int s0 = csr[e], s1 = csr[e + 1];
        float q0 = a_s[s0 * 4 + hd] + adh;
        float q1 = a_s[s1 * 4 + hd] + adh;
        unsigned hv0 = *(const unsigned*)(hh + s0 * 128 + c0);
        unsigned hv1 = *(const unsigned*)(hh + s1 * 128 + c0);
        q0 = (q0 > 0.f) ? q0 : 0.2f * q0;
        q1 = (q1 > 0.f) ? q1 : 0.2f * q1;
        float w0 = __expf(q0 - es), w1 = __expf(q1 - es);
        da += w0;
        a0 += w0 * bf2f((unsigned short)(hv0 & 0xFFFFu));
        a1 += w0 * bf2f((unsigned short)(hv0 >> 16));
        db += w1;
        b0v += w1 * bf2f((unsigned short)(hv1 & 0xFFFFu));
        b1v += w1 * bf2f((unsigned short)(hv1 >> 16));
    }
    if (e < e1) {
        int s0 = csr[e];
        float q0 = a_s[s0 * 4 + hd] + adh;
        unsigned hv0 = *(const unsigned*)(hh + s0 * 128 + c0);
        q0 = (q0 > 0.f) ? q0 : 0.2f * q0;
        float w0 = __expf(q0 - es);
        da += w0;
        a0 += w0 * bf2f((unsigned short)(hv0 & 0xFFFFu));
        a1 += w0 * bf2f((unsigned short)(hv0 >> 16));
    }
    da += db; a0 += b0v; a1 += b1v;
    float inv = 1.f / da;
    float o0 = a0 * inv + bg[c0];
    float o1 = a1 * inv + bg[c0 + 1];
    float s = o0 + o1, ss = o0 * o0 + o1 * o1;
#pragma unroll
    for (int m = 1; m <= 32; m <<= 1) {
        s += __shfl_xor(s, m, 64); ss += __shfl_xor(ss, m, 64);
    }
    float mu = s * (1.f / 128.f);
    float var = ss * (1.f / 128.f) - mu * mu;
    float rstd = rsqrtf(var + 1e-5f);
    float y0 = (o0 - mu) * rstd * gg[c0] + bgg[c0];
    float y1 = (o1 - mu) * rstd * gg[c0 + 1] + bgg[c0 + 1];
    float id0 = h[node * 128 + c0], id1 = h[node * 128 + c0 + 1];
    float r0 = silu(y0) + id0;
    float r1 = silu(y1) + id1;
    h[node * 128 + c0]     = r0;
    h[node * 128 + c0 + 1] = r1;
    if (hb) {
        unsigned pk = (unsigned)f2bf(r0) | ((unsigned)f2bf(r1) << 16);
        *(unsigned*)(hb + node * 128 + c0) = pk;
    }
}

// ---------------- mean pool per graph (batch is sorted) ----------------
__global__ void pool_kernel(const float* __restrict__ h, const int* __restrict__ batch,
                            float* __restrict__ pooled, float* __restrict__ cntArr) {
    int c = threadIdx.x;
    int r0 = blockIdx.x * 64;
    int rend = r0 + 64; if (rend > NN) rend = NN;
    int cur = batch[r0];
    float acc = 0.f;
    int run = 0;
    for (int r = r0; r < rend; ++r) {
        int b = batch[r];
        float v = h[r * 128 + c];
        if (b != cur) {
            atomicAdd(&pooled[cur * 128 + c], acc);
            if (c == 0) atomicAdd(&cntArr[cur], (float)run);
            acc = 0.f; run = 0; cur = b;
        }
        acc += v; run++;
    }
    atomicAdd(&pooled[cur * 128 + c], acc);
    if (c == 0) atomicAdd(&cntArr[cur], (float)run);
}

// ---------------- head: silu(LN(pooled/cnt @ Wp + bp)) -> out (dtype per flag) --------
__global__ void final_kernel(const float* __restrict__ pooled, const float* __restrict__ cntArr,
                             const float* __restrict__ Wp, const float* __restrict__ bp,
                             const float* __restrict__ gp, const float* __restrict__ bep,
                             const int* __restrict__ flag, void* __restrict__ outv) {
    __shared__ float p[128];
    __shared__ float red[128];
    int g = blockIdx.x, c = threadIdx.x;
    float cnt = cntArr[g]; if (cnt < 1.f) cnt = 1.f;
    p[c] = pooled[g * 128 + c] / cnt;
    __syncthreads();
    float acc = bp[c];
    for (int k = 0; k < 128; ++k) acc += p[k] * Wp[k * 128 + c];
    red[c] = acc;
    __syncthreads();
    if (c < 64) {
        float s = red[c] + red[c + 64];
#pragma unroll
        for (int m = 1; m <= 32; m <<= 1) s += __shfl_xor(s, m, 64);
        if (c == 0) red[0] = s;
    }
    __syncthreads();
    float mu = red[0] * (1.f / 128.f);
    __syncthreads();
    float dv = acc - mu;
    red[c] = dv * dv;
    __syncthreads();
    if (c < 64) {
        float s = red[c] + red[c + 64];
#pragma unroll
        for (int m = 1; m <= 32; m <<= 1) s += __shfl_xor(s, m, 64);
        if (c == 0) red[0] = s;
    }
    __syncthreads();
    float var = red[0] * (1.f / 128.f);
    float rstd = rsqrtf(var + 1e-5f);
    float y = dv * rstd * gp[c] + bep[c];
    float r = silu(y);
    if (*flag) ((float*)outv)[g * 128 + c] = r;
    else       ((unsigned short*)outv)[g * 128 + c] = f2bf(r);
}

extern "C" void kernel_launch(void* const* d_in, const int* in_sizes, int n_in,
                              void* d_out, int out_size, void* d_ws, size_t ws_size,
                              hipStream_t stream) {
    const void* x    = d_in[0];
    const int*  eidx = (const int*)d_in[1];
    const int*  batch= (const int*)d_in[2];

    char* ws = (char*)d_ws;
    size_t off = 0;
    auto alloc = [&](size_t bytes) {
        void* p = ws + off;
        off = (off + bytes + 255) & ~(size_t)255;
        return p;
    };
    int*            flag   = (int*)alloc(256);
    unsigned short* xs     = (unsigned short*)alloc((size_t)NN * 128 * 2);
    float*          P      = (float*)alloc((size_t)NPARAM * 4);
    float*          h      = (float*)alloc((size_t)NPAD * 128 * 4);
    unsigned short* hh     = (unsigned short*)alloc((size_t)NN * 128 * 2);
    float*          a_s    = (float*)alloc((size_t)NN * 4 * 4);
    float*          a_d    = (float*)alloc((size_t)NN * 4 * 4);
    int*            offs   = (int*)alloc((size_t)(NN + 1) * 4);
    int*            cursor = (int*)alloc((size_t)NN * 4);
    int*            counts = (int*)alloc((size_t)NN * 4);
    int*            csr    = (int*)alloc((size_t)EPE * 4);
    int*            parts  = (int*)alloc(256 * 4);
    unsigned short* WT     = (unsigned short*)alloc(4 * 16384 * 2);
    float*          pooled = (float*)alloc((size_t)(BGR * 128 + BGR) * 4);
    float*          cntArr = pooled + BGR * 128;
    // bf16 shadow of h — only if workspace has room
    unsigned short* hb = nullptr;
    if (off + (size_t)NN * 128 * 2 <= ws_size)
        hb = (unsigned short*)alloc((size_t)NN * 128 * 2);

    hipMemsetAsync(counts, 0, (size_t)NN * 4, stream);
    hipMemsetAsync(pooled, 0, (size_t)(BGR * 128 + BGR) * 4, stream);

    sniff_kernel<<<1, 256, 0, stream>>>((const unsigned short*)x, flag);
    convert_x<<<4096, 256, 0, stream>>>(x, flag, xs, NN * 128);
    convert_params<<<14, 256, 0, stream>>>(d_in[3], d_in[7], d_in[8], d_in[9],
                                           d_in[4], d_in[5], d_in[6],
                                           d_in[10], d_in[11], d_in[12],
                                           d_in[13], d_in[14], d_in[15], d_in[16],
                                           flag, P);
    transpose_w<<<4, 256, 0, stream>>>(P, WT);

    count_edges<<<(EPE + 255) / 256, 256, 0, stream>>>(eidx, counts);
    int nb = (NN + 255) / 256;
    scan1<<<nb, 256, 0, stream>>>(counts, offs, parts);
    scan2<<<1, 256, 0, stream>>>(parts, nb);
    scan3<<<nb, 256, 0, stream>>>(offs, parts, cursor);
    scatter_edges<<<(EPE + 255) / 256, 256, 0, stream>>>(eidx, cursor, csr);

    gemm_encoder<<<NPAD / 64, 256, 0, stream>>>(xs, WT, P + OB0, P + OG0, P + OBE0, h, hb);
    for (int l = 0; l < 3; ++l) {
        if (hb)
            gemm_gat<1><<<NPAD / 64, 256, 0, stream>>>(h, hb, WT + (l + 1) * 16384,
                                                       P + OATTS + l * 128, P + OATTD + l * 128,
                                                       hh, a_s, a_d);
        else
            gemm_gat<0><<<NPAD / 64, 256, 0, stream>>>(h, hb, WT + (l + 1) * 16384,
                                                       P + OATTS + l * 128, P + OATTD + l * 128,
                                                       hh, a_s, a_d);
        gat_aggregate<<<NN / 4, 256, 0, stream>>>(offs, csr, a_s, a_d, hh, h, hb,
                                                  P + OBG + l * 128, P + OGG + l * 128,
                                                  P + OBGG + l * 128);
    }
    pool_kernel<<<(NN + 63) / 64, 128, 0, stream>>>(h, batch, pooled, cntArr);
    final_kernel<<<BGR, 128, 0, stream>>>(pooled, cntArr, P + OWP, P + OBP, P + OGP, P + OBEP,
                                          flag, d_out);
}

// Round 4
// 485.871 us; speedup vs baseline: 1.4297x; 1.1999x over previous
//
#include <hip/hip_runtime.h>

#define NN    50000
#define EE    800000
#define EPE   850000     // EE + NN self loops
#define NPAD  50048      // multiple of 64
#define BGR   64

// packed f32 param buffer offsets (floats)
#define OW0   0
#define OWG   16384
#define OATTS 65536
#define OATTD 65920
#define OB0   66304
#define OG0   66432
#define OBE0  66560
#define OBG   66688
#define OGG   67072
#define OBGG  67456
#define OWP   67840
#define OBP   84224
#define OGP   84352
#define OBEP  84480
#define NPARAM 84608

typedef __attribute__((ext_vector_type(8))) short bf16x8;
typedef __attribute__((ext_vector_type(4))) float f32x4;

__device__ __forceinline__ float bf2f(unsigned short u) {
    return __uint_as_float(((unsigned)u) << 16);
}
__device__ __forceinline__ unsigned short f2bf(float f) {
    unsigned u = __float_as_uint(f);
    unsigned r = (u + 0x7FFFu + ((u >> 16) & 1u)) >> 16;
    return (unsigned short)r;
}
__device__ __forceinline__ float silu(float y) { return y / (1.f + __expf(-y)); }

// ---------------- dtype sniff: f32 (flag=1) vs bf16 (flag=0) ----------------
__global__ void sniff_kernel(const unsigned short* __restrict__ xr, int* __restrict__ flag) {
    __shared__ int cnt;
    if (threadIdx.x == 0) cnt = 0;
    __syncthreads();
    int c = 0;
    for (int i = threadIdx.x; i < 4096; i += 256) {
        unsigned e = (xr[i] >> 7) & 0xFFu;
        if (e >= 134u) c++;
    }
    atomicAdd(&cnt, c);
    __syncthreads();
    if (threadIdx.x == 0) *flag = (cnt > 64) ? 1 : 0;
}

// ---------------- canonicalize all weights/vectors -> packed f32 buffer ----------------
// one element per thread; fully parallel (fixes 74us latency-serialized version)
__global__ void convert_params(const void* W0, const void* Wg, const void* atts, const void* attd,
                               const void* b0, const void* g0, const void* be0,
                               const void* bg, const void* gg, const void* bgg,
                               const void* Wp, const void* bp, const void* gp, const void* bep,
                               const int* __restrict__ flag, float* __restrict__ P) {
    int i = blockIdx.x * 256 + threadIdx.x;
    if (i >= NPARAM) return;
    const void* src; int j;
    if      (i < OWG)   { src = W0;   j = i - OW0; }
    else if (i < OATTS) { src = Wg;   j = i - OWG; }
    else if (i < OATTD) { src = atts; j = i - OATTS; }
    else if (i < OB0)   { src = attd; j = i - OATTD; }
    else if (i < OG0)   { src = b0;   j = i - OB0; }
    else if (i < OBE0)  { src = g0;   j = i - OG0; }
    else if (i < OBG)   { src = be0;  j = i - OBE0; }
    else if (i < OGG)   { src = bg;   j = i - OBG; }
    else if (i < OBGG)  { src = gg;   j = i - OGG; }
    else if (i < OWP)   { src = bgg;  j = i - OBGG; }
    else if (i < OBP)   { src = Wp;   j = i - OWP; }
    else if (i < OGP)   { src = bp;   j = i - OBP; }
    else if (i < OBEP)  { src = gp;   j = i - OGP; }
    else                { src = bep;  j = i - OBEP; }
    P[i] = (*flag) ? ((const float*)src)[j] : bf2f(((const unsigned short*)src)[j]);
}

// ---------------- weight transpose: WT[m][col][k] = W[m][k][col], bf16 ----------------
__global__ void transpose_w(const float* __restrict__ P, unsigned short* __restrict__ WT) {
    __shared__ unsigned short tile[128][129];
    int m = blockIdx.x;
    const float* src = P + (m == 0 ? OW0 : OWG + (m - 1) * 16384);
    unsigned short* dst = WT + m * 16384;
    for (int i = threadIdx.x; i < 16384; i += 256) tile[i >> 7][i & 127] = f2bf(src[i]);
    __syncthreads();
    for (int i = threadIdx.x; i < 16384; i += 256) {
        int c = i >> 7, k = i & 127;
        dst[i] = tile[k][c];
    }
}

// ---------------- CSR build ----------------
__global__ void count_edges(const int* __restrict__ eidx, int* __restrict__ counts) {
    int i = blockIdx.x * 256 + threadIdx.x;
    if (i >= EPE) return;
    int d = (i < EE) ? eidx[EE + i] : (i - EE);
    atomicAdd(&counts[d], 1);
}

__global__ void scan1(const int* __restrict__ counts, int* __restrict__ offs,
                      int* __restrict__ partials) {
    __shared__ int sm[256];
    int t = threadIdx.x, i = blockIdx.x * 256 + t;
    int x = (i < NN) ? counts[i] : 0;
    sm[t] = x; __syncthreads();
    for (int d = 1; d < 256; d <<= 1) {
        int v = (t >= d) ? sm[t - d] : 0;
        __syncthreads(); sm[t] += v; __syncthreads();
    }
    if (i < NN) offs[i] = sm[t] - x;
    if (t == 255) partials[blockIdx.x] = sm[255];
}

__global__ void scan2(int* __restrict__ partials, int nb) {
    __shared__ int sm[256];
    int t = threadIdx.x;
    int x = (t < nb) ? partials[t] : 0;
    sm[t] = x; __syncthreads();
    for (int d = 1; d < 256; d <<= 1) {
        int v = (t >= d) ? sm[t - d] : 0;
        __syncthreads(); sm[t] += v; __syncthreads();
    }
    if (t < nb) partials[t] = sm[t] - x;
}

__global__ void scan3(int* __restrict__ offs, const int* __restrict__ partials,
                      int* __restrict__ cursor) {
    int i = blockIdx.x * 256 + threadIdx.x;
    if (i < NN) {
        int v = offs[i] + partials[blockIdx.x];
        offs[i] = v; cursor[i] = v;
    }
    if (i == 0) offs[NN] = EPE;
}

__global__ void scatter_edges(const int* __restrict__ eidx, int* __restrict__ cursor,
                              int* __restrict__ csr, int* __restrict__ csr_dst) {
    int i = blockIdx.x * 256 + threadIdx.x;
    if (i >= EPE) return;
    int s, d;
    if (i < EE) { s = eidx[i]; d = eidx[EE + i]; } else { s = i - EE; d = i - EE; }
    int pos = atomicAdd(&cursor[d], 1);
    csr[pos] = s;
    csr_dst[pos] = d;
}

// ---------------- encoder GEMM: h = silu(LN(x@W0 + b0)), inline dtype handling --------
__global__ __launch_bounds__(256) void gemm_encoder(
    const void* __restrict__ xin, const int* __restrict__ flag,
    const unsigned short* __restrict__ WT,
    const float* __restrict__ b0, const float* __restrict__ g0,
    const float* __restrict__ be0, float* __restrict__ h) {
    int f = *flag;
    int wave = threadIdx.x >> 6, lane = threadIdx.x & 63;
    int cl = lane & 15, q = lane >> 4;
    int row0 = blockIdx.x * 64 + wave * 16;
    int rA = row0 + cl; if (rA >= NN) rA = NN - 1;
    int kq = q * 8;
    f32x4 acc[8];
#pragma unroll
    for (int t = 0; t < 8; ++t) acc[t] = (f32x4){0.f, 0.f, 0.f, 0.f};
#pragma unroll
    for (int k0 = 0; k0 < 128; k0 += 32) {
        bf16x8 a;
        if (f) {
            const float* xr = (const float*)xin + rA * 128 + k0 + kq;
            f32x4 f0 = *(const f32x4*)(xr);
            f32x4 f1 = *(const f32x4*)(xr + 4);
#pragma unroll
            for (int j = 0; j < 4; ++j) {
                a[j] = (short)f2bf(f0[j]);
                a[4 + j] = (short)f2bf(f1[j]);
            }
        } else {
            a = *(const bf16x8*)((const unsigned short*)xin + rA * 128 + k0 + kq);
        }
#pragma unroll
        for (int t = 0; t < 8; ++t) {
            bf16x8 b = *(const bf16x8*)(WT + (t * 16 + cl) * 128 + k0 + kq);
            acc[t] = __builtin_amdgcn_mfma_f32_16x16x32_bf16(a, b, acc[t], 0, 0, 0);
        }
    }
    float bcol[8], gcol[8], becol[8];
#pragma unroll
    for (int t = 0; t < 8; ++t) {
        int c = t * 16 + cl;
        bcol[t] = b0[c]; gcol[t] = g0[c]; becol[t] = be0[c];
    }
#pragma unroll
    for (int r = 0; r < 4; ++r) {
        int row = row0 + q * 4 + r;
        float v[8], s = 0.f, ss = 0.f;
#pragma unroll
        for (int t = 0; t < 8; ++t) {
            v[t] = acc[t][r] + bcol[t];
            s += v[t]; ss += v[t] * v[t];
        }
#pragma unroll
        for (int m = 1; m <= 8; m <<= 1) {
            s += __shfl_xor(s, m, 64); ss += __shfl_xor(ss, m, 64);
        }
        float mu = s * (1.f / 128.f);
        float var = ss * (1.f / 128.f) - mu * mu;
        float rstd = rsqrtf(var + 1e-5f);
        if (row < NN) {
#pragma unroll
            for (int t = 0; t < 8; ++t) {
                float y = (v[t] - mu) * rstd * gcol[t] + becol[t];
                h[row * 128 + t * 16 + cl] = silu(y);
            }
        }
    }
}

// ---------------- GAT GEMM: hh = h@Wg[l] (bf16), a_s/a_d/es per node ----------------
__global__ __launch_bounds__(256) void gemm_gat(
    const float* __restrict__ h, const unsigned short* __restrict__ WT,
    const float* __restrict__ atts, const float* __restrict__ attd,
    unsigned short* __restrict__ hh, float* __restrict__ a_s, float* __restrict__ a_d,
    float* __restrict__ es) {
    int wave = threadIdx.x >> 6, lane = threadIdx.x & 63;
    int cl = lane & 15, q = lane >> 4;
    int row0 = blockIdx.x * 64 + wave * 16;
    int rA = row0 + cl; if (rA >= NN) rA = NN - 1;
    int kq = q * 8;
    f32x4 acc[8];
#pragma unroll
    for (int t = 0; t < 8; ++t) acc[t] = (f32x4){0.f, 0.f, 0.f, 0.f};
#pragma unroll
    for (int k0 = 0; k0 < 128; k0 += 32) {
        const float* hrow = h + rA * 128;
        f32x4 f0 = *(const f32x4*)(hrow + k0 + kq);
        f32x4 f1 = *(const f32x4*)(hrow + k0 + kq + 4);
        bf16x8 a;
#pragma unroll
        for (int j = 0; j < 4; ++j) {
            a[j] = (short)f2bf(f0[j]);
            a[4 + j] = (short)f2bf(f1[j]);
        }
#pragma unroll
        for (int t = 0; t < 8; ++t) {
            bf16x8 b = *(const bf16x8*)(WT + (t * 16 + cl) * 128 + k0 + kq);
            acc[t] = __builtin_amdgcn_mfma_f32_16x16x32_bf16(a, b, acc[t], 0, 0, 0);
        }
    }
#pragma unroll
    for (int r = 0; r < 4; ++r) {
        int row = row0 + q * 4 + r;
        if (row < NN) {
#pragma unroll
            for (int t = 0; t < 8; ++t)
                hh[row * 128 + t * 16 + cl] = f2bf(acc[t][r]);
        }
    }
    float as_lo[4], as_hi[4], ad_lo[4], ad_hi[4];
#pragma unroll
    for (int hd = 0; hd < 4; ++hd) {
        as_lo[hd] = atts[hd * 32 + cl];      as_hi[hd] = atts[hd * 32 + 16 + cl];
        ad_lo[hd] = attd[hd * 32 + cl];      ad_hi[hd] = attd[hd * 32 + 16 + cl];
    }
#pragma unroll
    for (int r = 0; r < 4; ++r) {
        int row = row0 + q * 4 + r;
        float ps[4], pd[4];
#pragma unroll
        for (int hd = 0; hd < 4; ++hd) {
            float v0 = acc[2 * hd][r], v1 = acc[2 * hd + 1][r];
            ps[hd] = v0 * as_lo[hd] + v1 * as_hi[hd];
            pd[hd] = v0 * ad_lo[hd] + v1 * ad_hi[hd];
        }
#pragma unroll
        for (int m = 1; m <= 8; m <<= 1) {
#pragma unroll
            for (int hd = 0; hd < 4; ++hd) {
                ps[hd] += __shfl_xor(ps[hd], m, 64);
                pd[hd] += __shfl_xor(pd[hd], m, 64);
            }
        }
        if (row < NN && cl < 4) {
            float vs = (cl == 0) ? ps[0] : (cl == 1) ? ps[1] : (cl == 2) ? ps[2] : ps[3];
            float vd = (cl == 0) ? pd[0] : (cl == 1) ? pd[1] : (cl == 2) ? pd[2] : pd[3];
            a_s[row * 4 + cl] = vs;
            a_d[row * 4 + cl] = vd;
            float e = vs + vd;                       // self-loop logit
            es[row * 4 + cl] = (e > 0.f) ? e : 0.2f * e;
        }
    }
}

// ---------------- edge-parallel softmax weights: w[pos][hd] ----------------
__global__ void edge_weights(const int* __restrict__ csr, const int* __restrict__ csr_dst,
                             const float* __restrict__ a_s, const float* __restrict__ a_d,
                             const float* __restrict__ es, float* __restrict__ w) {
    int i = blockIdx.x * 256 + threadIdx.x;
    if (i >= EPE) return;
    int s = csr[i], d = csr_dst[i];
    f32x4 as = *(const f32x4*)(a_s + s * 4);
    f32x4 ad = *(const f32x4*)(a_d + d * 4);
    f32x4 e4 = *(const f32x4*)(es + d * 4);
    f32x4 out;
#pragma unroll
    for (int hd = 0; hd < 4; ++hd) {
        float q = as[hd] + ad[hd];
        q = (q > 0.f) ? q : 0.2f * q;
        out[hd] = __expf(q - e4[hd]);
    }
    *(f32x4*)(w + i * 4) = out;
}

// ---------------- per-node weighted aggregation + LN + SiLU + residual ----------------
__global__ __launch_bounds__(256) void gat_aggregate(
    const int* __restrict__ offs, const int* __restrict__ csr,
    const float* __restrict__ w, const unsigned short* __restrict__ hh,
    float* __restrict__ h,
    const float* __restrict__ bg, const float* __restrict__ gg,
    const float* __restrict__ bgg) {
    int node = blockIdx.x * 4 + (threadIdx.x >> 6);
    int lane = threadIdx.x & 63;
    if (node >= NN) return;
    int e0 = offs[node], e1 = offs[node + 1];
    int c0 = lane * 2, hd = lane >> 4;
    float d0 = 0.f, d1 = 0.f, d2 = 0.f, d3 = 0.f;
    float x0 = 0.f, y0 = 0.f, x1 = 0.f, y1 = 0.f;
    float x2 = 0.f, y2 = 0.f, x3 = 0.f, y3 = 0.f;
    int e = e0;
    for (; e + 4 <= e1; e += 4) {
        int s0 = csr[e], s1 = csr[e + 1], s2 = csr[e + 2], s3 = csr[e + 3];
        float w0 = w[(e + 0) * 4 + hd];
        float w1 = w[(e + 1) * 4 + hd];
        float w2 = w[(e + 2) * 4 + hd];
        float w3 = w[(e + 3) * 4 + hd];
        unsigned v0 = *(const unsigned*)(hh + s0 * 128 + c0);
        unsigned v1 = *(const unsigned*)(hh + s1 * 128 + c0);
        unsigned v2 = *(const unsigned*)(hh + s2 * 128 + c0);
        unsigned v3 = *(const unsigned*)(hh + s3 * 128 + c0);
        d0 += w0; x0 += w0 * bf2f((unsigned short)(v0 & 0xFFFFu)); y0 += w0 * bf2f((unsigned short)(v0 >> 16));
        d1 += w1; x1 += w1 * bf2f((unsigned short)(v1 & 0xFFFFu)); y1 += w1 * bf2f((unsigned short)(v1 >> 16));
        d2 += w2; x2 += w2 * bf2f((unsigned short)(v2 & 0xFFFFu)); y2 += w2 * bf2f((unsigned short)(v2 >> 16));
        d3 += w3; x3 += w3 * bf2f((unsigned short)(v3 & 0xFFFFu)); y3 += w3 * bf2f((unsigned short)(v3 >> 16));
    }
    for (; e < e1; ++e) {
        int s0 = csr[e];
        float w0 = w[e * 4 + hd];
        unsigned v0 = *(const unsigned*)(hh + s0 * 128 + c0);
        d0 += w0; x0 += w0 * bf2f((unsigned short)(v0 & 0xFFFFu)); y0 += w0 * bf2f((unsigned short)(v0 >> 16));
    }
    float den = (d0 + d1) + (d2 + d3);
    float a0 = (x0 + x1) + (x2 + x3);
    float a1 = (y0 + y1) + (y2 + y3);
    float inv = 1.f / den;
    float o0 = a0 * inv + bg[c0];
    float o1 = a1 * inv + bg[c0 + 1];
    float s = o0 + o1, ss = o0 * o0 + o1 * o1;
#pragma unroll
    for (int m = 1; m <= 32; m <<= 1) {
        s += __shfl_xor(s, m, 64); ss += __shfl_xor(ss, m, 64);
    }
    float mu = s * (1.f / 128.f);
    float var = ss * (1.f / 128.f) - mu * mu;
    float rstd = rsqrtf(var + 1e-5f);
    float yy0 = (o0 - mu) * rstd * gg[c0] + bgg[c0];
    float yy1 = (o1 - mu) * rstd * gg[c0 + 1] + bgg[c0 + 1];
    float id0 = h[node * 128 + c0], id1 = h[node * 128 + c0 + 1];
    h[node * 128 + c0]     = silu(yy0) + id0;
    h[node * 128 + c0 + 1] = silu(yy1) + id1;
}

// ---------------- mean pool per graph (batch is sorted) ----------------
__global__ void pool_kernel(const float* __restrict__ h, const int* __restrict__ batch,
                            float* __restrict__ pooled, float* __restrict__ cntArr) {
    int c = threadIdx.x;
    int r0 = blockIdx.x * 64;
    int rend = r0 + 64; if (rend > NN) rend = NN;
    int cur = batch[r0];
    float acc = 0.f;
    int run = 0;
    for (int r = r0; r < rend; ++r) {
        int b = batch[r];
        float v = h[r * 128 + c];
        if (b != cur) {
            atomicAdd(&pooled[cur * 128 + c], acc);
            if (c == 0) atomicAdd(&cntArr[cur], (float)run);
            acc = 0.f; run = 0; cur = b;
        }
        acc += v; run++;
    }
    atomicAdd(&pooled[cur * 128 + c], acc);
    if (c == 0) atomicAdd(&cntArr[cur], (float)run);
}

// ---------------- head: silu(LN(pooled/cnt @ Wp + bp)) -> out (dtype per flag) --------
__global__ void final_kernel(const float* __restrict__ pooled, const float* __restrict__ cntArr,
                             const float* __restrict__ Wp, const float* __restrict__ bp,
                             const float* __restrict__ gp, const float* __restrict__ bep,
                             const int* __restrict__ flag, void* __restrict__ outv) {
    __shared__ float p[128];
    __shared__ float red[128];
    int g = blockIdx.x, c = threadIdx.x;
    float cnt = cntArr[g]; if (cnt < 1.f) cnt = 1.f;
    p[c] = pooled[g * 128 + c] / cnt;
    __syncthreads();
    float acc = bp[c];
    for (int k = 0; k < 128; ++k) acc += p[k] * Wp[k * 128 + c];
    red[c] = acc;
    __syncthreads();
    if (c < 64) {
        float s = red[c] + red[c + 64];
#pragma unroll
        for (int m = 1; m <= 32; m <<= 1) s += __shfl_xor(s, m, 64);
        if (c == 0) red[0] = s;
    }
    __syncthreads();
    float mu = red[0] * (1.f / 128.f);
    __syncthreads();
    float dv = acc - mu;
    red[c] = dv * dv;
    __syncthreads();
    if (c < 64) {
        float s = red[c] + red[c + 64];
#pragma unroll
        for (int m = 1; m <= 32; m <<= 1) s += __shfl_xor(s, m, 64);
        if (c == 0) red[0] = s;
    }
    __syncthreads();
    float var = red[0] * (1.f / 128.f);
    float rstd = rsqrtf(var + 1e-5f);
    float y = dv * rstd * gp[c] + bep[c];
    float r = silu(y);
    if (*flag) ((float*)outv)[g * 128 + c] = r;
    else       ((unsigned short*)outv)[g * 128 + c] = f2bf(r);
}

extern "C" void kernel_launch(void* const* d_in, const int* in_sizes, int n_in,
                              void* d_out, int out_size, void* d_ws, size_t ws_size,
                              hipStream_t stream) {
    const void* x    = d_in[0];
    const int*  eidx = (const int*)d_in[1];
    const int*  batch= (const int*)d_in[2];

    char* ws = (char*)d_ws;
    size_t off = 0;
    auto alloc = [&](size_t bytes) {
        void* p = ws + off;
        off = (off + bytes + 255) & ~(size_t)255;
        return p;
    };
    int*            flag    = (int*)alloc(256);
    float*          P       = (float*)alloc((size_t)NPARAM * 4);
    float*          h       = (float*)alloc((size_t)NPAD * 128 * 4);
    unsigned short* hh      = (unsigned short*)alloc((size_t)NN * 128 * 2);
    float*          a_s     = (float*)alloc((size_t)NN * 4 * 4);
    float*          a_d     = (float*)alloc((size_t)NN * 4 * 4);
    float*          es      = (float*)alloc((size_t)NN * 4 * 4);
    int*            offs    = (int*)alloc((size_t)(NN + 1) * 4);
    int*            cursor  = (int*)alloc((size_t)NN * 4);
    int*            counts  = (int*)alloc((size_t)NN * 4);
    int*            csr     = (int*)alloc((size_t)EPE * 4);
    int*            csr_dst = (int*)alloc((size_t)EPE * 4);
    float*          w       = (float*)alloc((size_t)EPE * 4 * 4);
    int*            parts   = (int*)alloc(256 * 4);
    unsigned short* WT      = (unsigned short*)alloc(4 * 16384 * 2);
    float*          pooled  = (float*)alloc((size_t)(BGR * 128 + BGR) * 4);
    float*          cntArr  = pooled + BGR * 128;

    hipMemsetAsync(counts, 0, (size_t)NN * 4, stream);
    hipMemsetAsync(pooled, 0, (size_t)(BGR * 128 + BGR) * 4, stream);

    sniff_kernel<<<1, 256, 0, stream>>>((const unsigned short*)x, flag);
    convert_params<<<(NPARAM + 255) / 256, 256, 0, stream>>>(
        d_in[3], d_in[7], d_in[8], d_in[9],
        d_in[4], d_in[5], d_in[6],
        d_in[10], d_in[11], d_in[12],
        d_in[13], d_in[14], d_in[15], d_in[16],
        flag, P);
    transpose_w<<<4, 256, 0, stream>>>(P, WT);

    count_edges<<<(EPE + 255) / 256, 256, 0, stream>>>(eidx, counts);
    int nb = (NN + 255) / 256;
    scan1<<<nb, 256, 0, stream>>>(counts, offs, parts);
    scan2<<<1, 256, 0, stream>>>(parts, nb);
    scan3<<<nb, 256, 0, stream>>>(offs, parts, cursor);
    scatter_edges<<<(EPE + 255) / 256, 256, 0, stream>>>(eidx, cursor, csr, csr_dst);

    gemm_encoder<<<NPAD / 64, 256, 0, stream>>>(x, flag, WT, P + OB0, P + OG0, P + OBE0, h);
    for (int l = 0; l < 3; ++l) {
        gemm_gat<<<NPAD / 64, 256, 0, stream>>>(h, WT + (l + 1) * 16384,
                                                P + OATTS + l * 128, P + OATTD + l * 128,
                                                hh, a_s, a_d, es);
        edge_weights<<<(EPE + 255) / 256, 256, 0, stream>>>(csr, csr_dst, a_s, a_d, es, w);
        gat_aggregate<<<NN / 4, 256, 0, stream>>>(offs, csr, w, hh, h,
                                                  P + OBG + l * 128, P + OGG + l * 128,
                                                  P + OBGG + l * 128);
    }
    pool_kernel<<<(NN + 63) / 64, 128, 0, stream>>>(h, batch, pooled, cntArr);
    final_kernel<<<BGR, 128, 0, stream>>>(pooled, cntArr, P + OWP, P + OBP, P + OGP, P + OBEP,
                                          flag, d_out);
}